// Round 7
// baseline (108.443 us; speedup 1.0000x reference)
//
#include <hip/hip_runtime.h>

// ---------------------------------------------------------------------------
// KAN conv layer: out[b,o,i,j] = sum_{c,p} silu(patch)*bw[o,c,p]
//                              + sum_{c,p,g} Bspline_g(patch)*sw[o,c,p,g]*sc[o,c,p]
// B=16 CIN=32 COUT=64 H=W=64 K=3 -> Ho=Wo=62, P=9, G+k=8 bases
// bf16 MFMA implicit GEMM, K = 2592 = 81 steps of 32 (72 spline + 9 silu).
// R6: 2 waves/SIMD (o-split) -> ~28us, LDS-read-bound: o-split wave = 8 MFMA
//     per 6 frag-reads -> 48 KB/step/CU > 2x what the matrix pipe needs.
// R7: keep 2 waves/SIMD but via in-block split-K: wave (kh, r) = full 4x4
//     64x64 tile (16 MFMA : 8 frags, best ratio) over K-half kh. LDS reads
//     drop 1.5x (2.6 MB/block). 120 KB single-buffered stage (both halves),
//     LDS tree-reduction at end. Grid 256 = 1 block/CU.
// ---------------------------------------------------------------------------

typedef short v8s __attribute__((ext_vector_type(8)));
typedef float v4f __attribute__((ext_vector_type(4)));

#define FSPL_OFF   0u
#define FSILU_OFF  33554688u          // 33554432 (Fspl) + 256 pad
#define WPACK_OFF  37749248u          // FSILU_OFF + 4194304 (Fsil) + 256 pad

__device__ __forceinline__ unsigned short f2bf(float f) {
  unsigned int u = __float_as_uint(f);
  u += 0x7fffu + ((u >> 16) & 1u);          // round-to-nearest-even
  return (unsigned short)(u >> 16);
}

// ---- kernel 1: spline bases per input element -> Fspl[b][c][y][x][g8] ------
__global__ __launch_bounds__(256) void k_spline(const float* __restrict__ x,
                                                unsigned char* __restrict__ ws) {
  int pix = blockIdx.x * 256 + threadIdx.x;      // 2,097,152 elements
  float v = x[pix];
  float bb[11];
#pragma unroll
  for (int i = 0; i < 11; ++i) {
    float t0 = -2.2f + 0.4f * i;
    bb[i] = (v >= t0 && v < t0 + 0.4f) ? 1.0f : 0.0f;
  }
#pragma unroll
  for (int j = 1; j <= 3; ++j) {
    float rj = 1.0f / (0.4f * j);
#pragma unroll
    for (int i = 0; i + j < 11; ++i) {
      float ti = -2.2f + 0.4f * i;
      float lf = (v - ti) * rj;
      float rt = ((ti + 0.4f * (j + 1)) - v) * rj;
      bb[i] = lf * bb[i] + rt * bb[i + 1];
    }
  }
  uint4 o;
  o.x = (unsigned)f2bf(bb[0]) | ((unsigned)f2bf(bb[1]) << 16);
  o.y = (unsigned)f2bf(bb[2]) | ((unsigned)f2bf(bb[3]) << 16);
  o.z = (unsigned)f2bf(bb[4]) | ((unsigned)f2bf(bb[5]) << 16);
  o.w = (unsigned)f2bf(bb[6]) | ((unsigned)f2bf(bb[7]) << 16);
  *(uint4*)(ws + FSPL_OFF + (size_t)pix * 16) = o;
}

// ---- kernel 2: silu, transposed -> Fsil[b][y][x][c32] ----------------------
__global__ __launch_bounds__(256) void k_silu(const float* __restrict__ x,
                                              unsigned char* __restrict__ ws) {
  int bid = blockIdx.x;                  // b*64 + y
  int b = bid >> 6, y = bid & 63;
  int t = threadIdx.x;
  int xx = t & 63, cg = t >> 6;
  unsigned short h[8];
#pragma unroll
  for (int k = 0; k < 8; ++k) {
    int c = cg * 8 + k;
    float v = x[(((size_t)(b * 32 + c) * 64 + y) * 64) + xx];
    float s = v / (1.0f + __expf(-v));
    h[k] = f2bf(s);
  }
  uint4 o;
  o.x = (unsigned)h[0] | ((unsigned)h[1] << 16);
  o.y = (unsigned)h[2] | ((unsigned)h[3] << 16);
  o.z = (unsigned)h[4] | ((unsigned)h[5] << 16);
  o.w = (unsigned)h[6] | ((unsigned)h[7] << 16);
  *(uint4*)(ws + FSILU_OFF + (size_t)(b * 4096 + y * 64 + xx) * 64 + cg * 16) = o;
}

// ---- kernel 3: pack weights in MFMA A-fragment order -----------------------
__global__ __launch_bounds__(256) void k_wpack(const float* __restrict__ bw,
                                               const float* __restrict__ sw,
                                               const float* __restrict__ sc,
                                               unsigned char* __restrict__ ws) {
  int tid = blockIdx.x * 256 + threadIdx.x;
  if (tid >= 165888) return;             // 81*4*64*8
  int e = tid & 7, lane = (tid >> 3) & 63, ot = (tid >> 9) & 3, s = tid >> 11;
  int k = s * 32 + ((lane >> 4) << 3) + e;
  int o = (ot << 4) + (lane & 15);
  float val;
  if (k < 2304) {
    int chunk = k / 24, u = k - chunk * 24;
    int dj = u >> 3, g = u & 7;
    int c = chunk / 3, di = chunk - c * 3;
    int p = di * 3 + dj;
    val = sw[((size_t)(o * 32 + c) * 9 + p) * 8 + g] * sc[(size_t)(o * 32 + c) * 9 + p];
  } else {
    int k2 = k - 2304;
    int tp = k2 >> 5, cc = k2 & 31;
    val = bw[(size_t)(o * 32 + cc) * 9 + tp];
  }
  *(unsigned short*)(ws + WPACK_OFF + (size_t)tid * 2) = f2bf(val);
}

// ---- async 16B global -> LDS (lds dest = wave-uniform base + lane*16) ------
__device__ __forceinline__ void ld16(unsigned char* ldsp, const unsigned char* gp) {
  __builtin_amdgcn_global_load_lds(
      (const __attribute__((address_space(1))) unsigned int*)gp,
      (__attribute__((address_space(3))) unsigned int*)ldsp, 16, 0, 0);
}

// ---- kernel 4: implicit GEMM, split-K halves, 4x4 acc per wave -------------
// Block: 8 waves = (kh = w>>2, r = w&3). Wave: 64o x 64j 4x4 MFMA tile over
// K-half kh. Round t (0..3): kh=0 uses period t (c 4t..4t+3), kh=1 period
// 4+t (c 16+4t..). Round 4 = silu (kh=0: taps 0-4, kh=1: taps 5-8).
// Stage per round: wl[0]+wl[1] (72 KB weights) + fl[0]+fl[1] (48 KB feats).
__global__ __launch_bounds__(512) void k_gemm(const unsigned char* __restrict__ ws,
                                              float* __restrict__ out) {
  __shared__ __align__(16) unsigned char wl[2][36864];
  __shared__ __align__(16) unsigned char fl[2][25088];   // 24 KB + overread pad

  const int blk = blockIdx.x;            // b*16 + ig   (256 blocks, 1/CU)
  const int b = blk >> 4, ig = blk & 15;
  const int i0 = ig * 4;                 // rows i0..i0+3 (62,63 masked)
  const int tid = threadIdx.x;
  const int wave = tid >> 6, lane = tid & 63;
  const int q = lane >> 4, ln = lane & 15;
  const int kh = wave >> 2, r = wave & 3;
  const int i = i0 + r;

  auto stage = [&](int t) {              // t = 0..3 spline rounds, 4 = silu
#pragma unroll
    for (int it = 0; it < 15; ++it) {    // 120 chunks of 1 KB over 8 waves
      const int u = wave + it * 8;
      if (t < 4) {
        if (u < 36) {                    // half-0 weights: steps 9t..9t+8
          ld16(&wl[0][u * 1024],
               ws + WPACK_OFF + (size_t)t * 36864 + (size_t)u * 1024 + lane * 16);
        } else if (u < 72) {             // half-1 weights: steps 9(4+t)..
          const int v = u - 36;
          ld16(&wl[1][v * 1024],
               ws + WPACK_OFF + (size_t)(4 + t) * 36864 + (size_t)v * 1024 + lane * 16);
        } else if (u < 96) {             // half-0 features: c = 4t+cp
          const int v = u - 72;
          const int cp = v / 6, rr = v - cp * 6;
          const int y = min(i0 + rr, 63);
          ld16(&fl[0][v * 1024],
               ws + FSPL_OFF + ((size_t)((b * 32 + t * 4 + cp) * 64 + y)) * 1024 + lane * 16);
        } else {                         // half-1 features: c = 16+4t+cp
          const int v = u - 96;
          const int cp = v / 6, rr = v - cp * 6;
          const int y = min(i0 + rr, 63);
          ld16(&fl[1][v * 1024],
               ws + FSPL_OFF + ((size_t)((b * 32 + 16 + t * 4 + cp) * 64 + y)) * 1024 + lane * 16);
        }
      } else {                           // silu round: 60 chunks only
        if (u < 36) {                    // weights steps 72..80
          ld16(&wl[0][u * 1024],
               ws + WPACK_OFF + (size_t)8 * 36864 + (size_t)u * 1024 + lane * 16);
        } else if (u >= 72 && u < 96) {  // silu rows, XOR-swizzled
          const int v = u - 72;
          const int rr = v >> 2, p4 = v & 3;
          const int y = min(i0 + rr, 63);
          ld16(&fl[0][v * 1024],
               ws + FSILU_OFF + (size_t)(b * 64 + y) * 4096 +
                   (p4 * 16 + (lane >> 2)) * 64 + ((lane & 3) ^ ((lane >> 2) & 3)) * 16);
        }
      }
    }
  };

  // per-lane spline fragment offsets within a staged period (row = r)
  int foff[9];
#pragma unroll
  for (int sg = 0; sg < 9; ++sg) {
    int rid = 4 * sg + q;
    int ch = rid / 3, sub = rid - ch * 3;
    int cp = ch / 3, di = ch - cp * 3;
    foff[sg] = (cp * 6 + r + di) * 1024 + (sub + ln) * 16;
  }

  v4f acc[4][4];
#pragma unroll
  for (int a = 0; a < 4; ++a)
#pragma unroll
    for (int c = 0; c < 4; ++c) acc[a][c] = (v4f){0.f, 0.f, 0.f, 0.f};

  stage(0);
  __syncthreads();

#pragma unroll 1
  for (int t = 0; t < 4; ++t) {
    const unsigned char* wb_base = wl[kh];
    const unsigned char* fb_base = fl[kh];
#pragma unroll
    for (int sg = 0; sg < 9; ++sg) {
      v8s wb[4], fb[4];
#pragma unroll
      for (int ot = 0; ot < 4; ++ot)
        wb[ot] = *(const v8s*)(wb_base + sg * 4096 + ot * 1024 + lane * 16);
#pragma unroll
      for (int pt = 0; pt < 4; ++pt)
        fb[pt] = *(const v8s*)(fb_base + foff[sg] + pt * 256);
#pragma unroll
      for (int ot = 0; ot < 4; ++ot)
#pragma unroll
        for (int pt = 0; pt < 4; ++pt)
          acc[ot][pt] = __builtin_amdgcn_mfma_f32_16x16x32_bf16(
              wb[ot], fb[pt], acc[ot][pt], 0, 0, 0);
    }
    __syncthreads();                     // all reads of round t done
    stage(t + 1);                        // t+1 == 4 -> silu round
    __syncthreads();                     // staged data visible
  }

  // ---- silu round: kh=0 taps 0..4, kh=1 taps 5..8 --------------------------
  const int p_lo = kh ? 5 : 0, p_hi = kh ? 9 : 5;
  for (int p = p_lo; p < p_hi; ++p) {
    const int di = p / 3, dj = p - di * 3;
    v8s wb[4], fb[4];
#pragma unroll
    for (int ot = 0; ot < 4; ++ot)
      wb[ot] = *(const v8s*)(&wl[0][0] + p * 4096 + ot * 1024 + lane * 16);
    const int xb = dj + ln;              // x = xb + pt*16; (x&3) == (xb&3)
    const int sbase = (r + di) * 4096 + xb * 64 + ((q ^ (xb & 3)) * 16);
#pragma unroll
    for (int pt = 0; pt < 4; ++pt)
      fb[pt] = *(const v8s*)(&fl[0][0] + sbase + pt * 1024);
#pragma unroll
    for (int ot = 0; ot < 4; ++ot)
#pragma unroll
      for (int pt = 0; pt < 4; ++pt)
        acc[ot][pt] = __builtin_amdgcn_mfma_f32_16x16x32_bf16(
            wb[ot], fb[pt], acc[ot][pt], 0, 0, 0);
  }

  // ---- reduction: kh=1 -> LDS (reuse weight buffers, 64 KB) -> kh=0 --------
  __syncthreads();
  float* red = (float*)&wl[0][0];
  if (kh == 1) {
    float* dst = red + r * 4096 + lane * 4;
#pragma unroll
    for (int ot = 0; ot < 4; ++ot)
#pragma unroll
      for (int pt = 0; pt < 4; ++pt)
        *(v4f*)(dst + (ot * 4 + pt) * 256) = acc[ot][pt];
  }
  __syncthreads();
  if (kh == 0) {
    const float* srcp = red + r * 4096 + lane * 4;
#pragma unroll
    for (int ot = 0; ot < 4; ++ot)
#pragma unroll
      for (int pt = 0; pt < 4; ++pt)
        acc[ot][pt] += *(const v4f*)(srcp + (ot * 4 + pt) * 256);

    // epilogue: C/D layout col(n=j)=lane&15, row(m=o)=q*4+reg
    if (i < 62) {
#pragma unroll
      for (int ot = 0; ot < 4; ++ot)
#pragma unroll
        for (int pt = 0; pt < 4; ++pt) {
          const int j = pt * 16 + ln;
          if (j < 62) {
#pragma unroll
            for (int rr = 0; rr < 4; ++rr) {
              const int o = ot * 16 + q * 4 + rr;
              out[(((size_t)b * 64 + o) * 62 + i) * 62 + j] = acc[ot][pt][rr];
            }
          }
        }
    }
  }
}

extern "C" void kernel_launch(void* const* d_in, const int* in_sizes, int n_in,
                              void* d_out, int out_size, void* d_ws, size_t ws_size,
                              hipStream_t stream) {
  const float* x  = (const float*)d_in[0];
  const float* bw = (const float*)d_in[1];
  const float* sw = (const float*)d_in[2];
  const float* sc = (const float*)d_in[3];
  unsigned char* ws = (unsigned char*)d_ws;
  float* out = (float*)d_out;

  hipLaunchKernelGGL(k_spline, dim3(8192), dim3(256), 0, stream, x, ws);
  hipLaunchKernelGGL(k_silu,   dim3(1024), dim3(256), 0, stream, x, ws);
  hipLaunchKernelGGL(k_wpack,  dim3(648),  dim3(256), 0, stream, bw, sw, sc, ws);
  hipLaunchKernelGGL(k_gemm,   dim3(256),  dim3(512), 0, stream, ws, out);
}

// Round 8
// 103.628 us; speedup vs baseline: 1.0465x; 1.0465x over previous
//
#include <hip/hip_runtime.h>

// ---------------------------------------------------------------------------
// KAN conv layer: out[b,o,i,j] = sum_{c,p} silu(patch)*bw[o,c,p]
//                              + sum_{c,p,g} Bspline_g(patch)*sw[o,c,p,g]*sc[o,c,p]
// B=16 CIN=32 COUT=64 H=W=64 K=3 -> Ho=Wo=62, P=9, G+k=8 bases
// Implicit GEMM, K = 2592 = 81 steps of 32 (72 spline + 9 silu).
// R6 (best, ~31us gemm): dbuf LDS stages, 8 waves (r, oh), LDS-read-bound at
//     3.89 MB/CU of bf16 fragments.
// R8: spline branch -> fp8 e4m3 (mfma_f32_16x16x32_fp8_fp8, same rate/K/CD
//     layout as bf16): spline frags+weights 8B/lane ds_read_b64 -> spline LDS
//     bytes halve (2.12 MB/CU total). Silu branch stays bf16, staged ONCE
//     up-front into dedicated buffers (hidden). Fspl 32->16 MB HBM.
// ---------------------------------------------------------------------------

typedef short v8s __attribute__((ext_vector_type(8)));
typedef float v4f __attribute__((ext_vector_type(4)));

#define FSPL8_OFF   0u             // 16*32*64*64*8 = 16,777,216
#define FSILU_OFF   16777472u      // + 4,194,304 -> 20,971,776
#define WPACK8_OFF  20972032u      // 72*4*64*8 = 147,456 (fp8 spline weights)
#define WPACKS_OFF  21119744u      // 9*4*64*16 = 36,864 (bf16 silu weights)

__device__ __forceinline__ unsigned short f2bf(float f) {
  unsigned int u = __float_as_uint(f);
  u += 0x7fffu + ((u >> 16) & 1u);          // round-to-nearest-even
  return (unsigned short)(u >> 16);
}

// ---- kernel 1: spline bases per input element -> Fspl8[b][c][y][x][g8] fp8 -
__global__ __launch_bounds__(256) void k_spline(const float* __restrict__ x,
                                                unsigned char* __restrict__ ws) {
  int pix = blockIdx.x * 256 + threadIdx.x;      // 2,097,152 elements
  float v = x[pix];
  float bb[11];
#pragma unroll
  for (int i = 0; i < 11; ++i) {
    float t0 = -2.2f + 0.4f * i;
    bb[i] = (v >= t0 && v < t0 + 0.4f) ? 1.0f : 0.0f;
  }
#pragma unroll
  for (int j = 1; j <= 3; ++j) {
    float rj = 1.0f / (0.4f * j);
#pragma unroll
    for (int i = 0; i + j < 11; ++i) {
      float ti = -2.2f + 0.4f * i;
      float lf = (v - ti) * rj;
      float rt = ((ti + 0.4f * (j + 1)) - v) * rj;
      bb[i] = lf * bb[i] + rt * bb[i + 1];
    }
  }
  uint2 o;
  unsigned w0 = __builtin_amdgcn_cvt_pk_fp8_f32(bb[0], bb[1], 0, false);
  w0 = __builtin_amdgcn_cvt_pk_fp8_f32(bb[2], bb[3], w0, true);
  unsigned w1 = __builtin_amdgcn_cvt_pk_fp8_f32(bb[4], bb[5], 0, false);
  w1 = __builtin_amdgcn_cvt_pk_fp8_f32(bb[6], bb[7], w1, true);
  o.x = w0; o.y = w1;
  *(uint2*)(ws + FSPL8_OFF + (size_t)pix * 8) = o;
}

// ---- kernel 2: silu, transposed -> Fsil[b][y][x][c32] bf16 -----------------
__global__ __launch_bounds__(256) void k_silu(const float* __restrict__ x,
                                              unsigned char* __restrict__ ws) {
  int bid = blockIdx.x;                  // b*64 + y
  int b = bid >> 6, y = bid & 63;
  int t = threadIdx.x;
  int xx = t & 63, cg = t >> 6;
  unsigned short h[8];
#pragma unroll
  for (int k = 0; k < 8; ++k) {
    int c = cg * 8 + k;
    float v = x[(((size_t)(b * 32 + c) * 64 + y) * 64) + xx];
    float s = v / (1.0f + __expf(-v));
    h[k] = f2bf(s);
  }
  uint4 o;
  o.x = (unsigned)h[0] | ((unsigned)h[1] << 16);
  o.y = (unsigned)h[2] | ((unsigned)h[3] << 16);
  o.z = (unsigned)h[4] | ((unsigned)h[5] << 16);
  o.w = (unsigned)h[6] | ((unsigned)h[7] << 16);
  *(uint4*)(ws + FSILU_OFF + (size_t)(b * 4096 + y * 64 + xx) * 64 + cg * 16) = o;
}

// ---- kernel 3: pack weights (spline fp8 frag order; silu bf16 frag order) --
__global__ __launch_bounds__(256) void k_wpack(const float* __restrict__ bw,
                                               const float* __restrict__ sw,
                                               const float* __restrict__ sc,
                                               unsigned char* __restrict__ ws) {
  int tid = blockIdx.x * 256 + threadIdx.x;
  if (tid >= 165888) return;             // 147456 spline + 18432 silu
  if (tid < 147456) {                    // spline: [s72][ot4][lane64][e8] fp8
    int e = tid & 7, lane = (tid >> 3) & 63, ot = (tid >> 9) & 3, s = tid >> 11;
    int k = s * 32 + ((lane >> 4) << 3) + e;       // < 2304
    int o = (ot << 4) + (lane & 15);
    int chunk = k / 24, u = k - chunk * 24;
    int dj = u >> 3, g = u & 7;
    int c = chunk / 3, di = chunk - c * 3;
    int p = di * 3 + dj;
    float val = sw[((size_t)(o * 32 + c) * 9 + p) * 8 + g] * sc[(size_t)(o * 32 + c) * 9 + p];
    ws[WPACK8_OFF + tid] =
        (unsigned char)(__builtin_amdgcn_cvt_pk_fp8_f32(val, 0.f, 0, false) & 0xff);
  } else {                               // silu: [sp9][ot4][lane64][e8] bf16
    int t2 = tid - 147456;
    int e = t2 & 7, lane = (t2 >> 3) & 63, ot = (t2 >> 9) & 3, sp = t2 >> 11;
    int o = (ot << 4) + (lane & 15);
    int cc = ((lane >> 4) << 3) + e;     // channel 0..31
    float val = bw[(size_t)(o * 32 + cc) * 9 + sp];
    *(unsigned short*)(ws + WPACKS_OFF + (size_t)t2 * 2) = f2bf(val);
  }
}

// ---- async 16B global -> LDS (lds dest = wave-uniform base + lane*16) ------
__device__ __forceinline__ void ld16(unsigned char* ldsp, const unsigned char* gp) {
  __builtin_amdgcn_global_load_lds(
      (const __attribute__((address_space(1))) unsigned int*)gp,
      (__attribute__((address_space(3))) unsigned int*)ldsp, 16, 0, 0);
}

// ---- kernel 4: implicit GEMM; fp8 spline (dbuf) + bf16 silu (pre-staged) ---
// Block: 8 waves = (r = w>>1 of 4 rows, oh = w&1 o-half). Per spline step:
// 2 fp8 w-frags (b64) + 4 fp8 f-frags (b64) -> 8 fp8 MFMA. Period = 9 steps:
// 18 KB weights + 4 c-planes x 6 rows x 512B = 12 KB features, dbuf.
// Silu: bf16, 36 KB weights + 24 KB features staged once at kernel start.
__global__ __launch_bounds__(512) void k_gemm(const unsigned char* __restrict__ ws,
                                              float* __restrict__ out) {
  __shared__ __align__(16) unsigned char wl8[2][18432];
  __shared__ __align__(16) unsigned char fl8[2][12544];   // 12 KB + overread pad
  __shared__ __align__(16) unsigned char wsil[36864];
  __shared__ __align__(16) unsigned char fsil[25088];     // 24 KB + overread pad

  const int blk = blockIdx.x;            // b*16 + ig   (256 blocks, 1/CU)
  const int b = blk >> 4, ig = blk & 15;
  const int i0 = ig * 4;                 // rows i0..i0+3 (62,63 masked)
  const int tid = threadIdx.x;
  const int wave = tid >> 6, lane = tid & 63;
  const int q = lane >> 4, ln = lane & 15;
  const int r = wave >> 1, oh = wave & 1;
  const int i = i0 + r;

  auto stage_spl = [&](int t, int bi) {  // 30 chunks: 18 weights + 12 features
#pragma unroll
    for (int it = 0; it < 4; ++it) {
      const int u = wave + it * 8;
      if (u < 18) {
        ld16(&wl8[bi][u * 1024],
             ws + WPACK8_OFF + (size_t)t * 18432 + (size_t)u * 1024 + lane * 16);
      } else if (u < 30) {
        const int v = u - 18;            // cp*3 + cr
        const int cp = v / 3, cr = v - cp * 3;   // chunk = rows {2cr, 2cr+1}
        ld16(&fl8[bi][v * 1024],
             ws + FSPL8_OFF +
                 ((size_t)((b * 32 + t * 4 + cp) * 64 + i0 + cr * 2)) * 512 + lane * 16);
      }
    }
  };

  auto stage_silu = [&]() {              // 60 chunks: 36 weights + 24 features
#pragma unroll
    for (int it = 0; it < 8; ++it) {
      const int u = wave + it * 8;
      if (u < 36) {
        ld16(&wsil[u * 1024], ws + WPACKS_OFF + (size_t)u * 1024 + lane * 16);
      } else if (u < 60) {
        const int v = u - 36;
        const int rr = v >> 2, p4 = v & 3;
        const int y = min(i0 + rr, 63);
        ld16(&fsil[v * 1024],
             ws + FSILU_OFF + (size_t)(b * 64 + y) * 4096 +
                 (p4 * 16 + (lane >> 2)) * 64 + ((lane & 3) ^ ((lane >> 2) & 3)) * 16);
      }
    }
  };

  // per-lane spline fragment offsets (fp8: 8 B/lane, chunk = cp*3KB + row*512)
  int foff[9];
#pragma unroll
  for (int sg = 0; sg < 9; ++sg) {
    int rid = 4 * sg + q;
    int ch = rid / 3, sub = rid - ch * 3;
    int cp = ch / 3, di = ch - cp * 3;
    foff[sg] = cp * 3072 + (r + di) * 512 + (sub + ln) * 8;
  }

  v4f acc[2][4];
#pragma unroll
  for (int a = 0; a < 2; ++a)
#pragma unroll
    for (int c = 0; c < 4; ++c) acc[a][c] = (v4f){0.f, 0.f, 0.f, 0.f};

  stage_silu();
  stage_spl(0, 0);
  __syncthreads();

#pragma unroll 1
  for (int t = 0; t < 8; ++t) {
    if (t < 7) stage_spl(t + 1, (t + 1) & 1);
    const unsigned char* wb_base = wl8[t & 1];
    const unsigned char* fb_base = fl8[t & 1];
#pragma unroll
    for (int sg = 0; sg < 9; ++sg) {
      long wb[2], fb[4];
#pragma unroll
      for (int tt = 0; tt < 2; ++tt)
        wb[tt] = *(const long*)(wb_base + sg * 2048 + (oh * 2 + tt) * 512 + lane * 8);
#pragma unroll
      for (int pt = 0; pt < 4; ++pt)
        fb[pt] = *(const long*)(fb_base + foff[sg] + pt * 128);
#pragma unroll
      for (int tt = 0; tt < 2; ++tt)
#pragma unroll
        for (int pt = 0; pt < 4; ++pt)
          acc[tt][pt] = __builtin_amdgcn_mfma_f32_16x16x32_fp8_fp8(
              wb[tt], fb[pt], acc[tt][pt], 0, 0, 0);
    }
    __syncthreads();
  }

  // ---- silu phase: bf16, from pre-staged buffers ---------------------------
#pragma unroll
  for (int e = 0; e < 9; ++e) {
    const int di = e / 3, dj = e % 3;
    v8s wb[2], fb[4];
#pragma unroll
    for (int tt = 0; tt < 2; ++tt)
      wb[tt] = *(const v8s*)(&wsil[0] + e * 4096 + (oh * 2 + tt) * 1024 + lane * 16);
    const int xb = dj + ln;              // x = xb + pt*16; (x&3) == (xb&3)
    const int sbase = (r + di) * 4096 + xb * 64 + ((q ^ (xb & 3)) * 16);
#pragma unroll
    for (int pt = 0; pt < 4; ++pt)
      fb[pt] = *(const v8s*)(&fsil[0] + sbase + pt * 1024);
#pragma unroll
    for (int tt = 0; tt < 2; ++tt)
#pragma unroll
      for (int pt = 0; pt < 4; ++pt)
        acc[tt][pt] = __builtin_amdgcn_mfma_f32_16x16x32_bf16(
            wb[tt], fb[pt], acc[tt][pt], 0, 0, 0);
  }

  // ---- epilogue: C/D layout col(n=j)=lane&15, row(m=o)=q*4+reg -------------
  if (i < 62) {
#pragma unroll
    for (int tt = 0; tt < 2; ++tt)
#pragma unroll
      for (int pt = 0; pt < 4; ++pt) {
        const int j = pt * 16 + ln;
        if (j < 62) {
#pragma unroll
          for (int rr = 0; rr < 4; ++rr) {
            const int o = (oh * 2 + tt) * 16 + q * 4 + rr;
            out[(((size_t)b * 64 + o) * 62 + i) * 62 + j] = acc[tt][pt][rr];
          }
        }
      }
  }
}

extern "C" void kernel_launch(void* const* d_in, const int* in_sizes, int n_in,
                              void* d_out, int out_size, void* d_ws, size_t ws_size,
                              hipStream_t stream) {
  const float* x  = (const float*)d_in[0];
  const float* bw = (const float*)d_in[1];
  const float* sw = (const float*)d_in[2];
  const float* sc = (const float*)d_in[3];
  unsigned char* ws = (unsigned char*)d_ws;
  float* out = (float*)d_out;

  hipLaunchKernelGGL(k_spline, dim3(8192), dim3(256), 0, stream, x, ws);
  hipLaunchKernelGGL(k_silu,   dim3(1024), dim3(256), 0, stream, x, ws);
  hipLaunchKernelGGL(k_wpack,  dim3(648),  dim3(256), 0, stream, bw, sw, sc, ws);
  hipLaunchKernelGGL(k_gemm,   dim3(256),  dim3(512), 0, stream, ws, out);
}

// Round 9
// 100.243 us; speedup vs baseline: 1.0818x; 1.0338x over previous
//
#include <hip/hip_runtime.h>

// ---------------------------------------------------------------------------
// KAN conv layer: out[b,o,i,j] = sum_{c,p} silu(patch)*bw[o,c,p]
//                              + sum_{c,p,g} Bspline_g(patch)*sw[o,c,p,g]*sc[o,c,p]
// B=16 CIN=32 COUT=64 H=W=64 K=3 -> Ho=Wo=62, P=9, G+k=8 bases
// Implicit GEMM. Spline K=2304 fp8; silu K=288 bf16.
// R8 (103.6us): fp8 spline, dbuf LDS stages, matrix-pipe-bound (~310cyc/step
//     /SIMD vs ~80 LDS).
// R9: spline periods -> 2x MX-scaled K=128 supersteps + 1 fp8 K=32 step
//     (mfma_scale_f32_16x16x128_f8f6f4, scale=1.0): spline matrix time
//     halves (2x MX rate). Weight bytes repacked [p][ss][ot][piece][lane][16]
//     (piece-split keeps b128 lane stride 16B); features assembled from the
//     same 8B runs as R8 (4x ds_read_b64 per frag). k-identity:
//     k = 288p+128ss+32q+8qo+e == old step (9p+4ss+q, run qo) byte-exact.
//     Also merged k_spline+k_silu into k_feat (one x read, one dispatch less).
// ---------------------------------------------------------------------------

typedef short v8s __attribute__((ext_vector_type(8)));
typedef float v4f __attribute__((ext_vector_type(4)));
typedef int   v4i __attribute__((ext_vector_type(4)));
typedef int   v8i __attribute__((ext_vector_type(8)));

#define FSPL8_OFF   0u             // 16*32*64*64*8 = 16,777,216
#define FSILU_OFF   16777472u      // + 4,194,304 -> 20,971,776
#define WMX_OFF     20972032u      // 8*2*4*2*64*16 = 131,072 (MX spline w)
#define WF8_OFF     21103104u      // 8*4*64*8 = 16,384 (leftover fp8 w)
#define WPACKS_OFF  21119488u      // 9*4*64*16 = 36,864 (bf16 silu w)

#define SCALE1 0x7F7F7F7Fu         // E8M0 127 = 1.0 in every byte

__device__ __forceinline__ unsigned short f2bf(float f) {
  unsigned int u = __float_as_uint(f);
  u += 0x7fffu + ((u >> 16) & 1u);          // round-to-nearest-even
  return (unsigned short)(u >> 16);
}

// ---- kernel 1: fused features: fp8 bases + bf16 silu, one read of x --------
__global__ __launch_bounds__(256) void k_feat(const float* __restrict__ x,
                                              unsigned char* __restrict__ ws) {
  const int bid = blockIdx.x;              // b*64 + y  (1024 blocks)
  const int b = bid >> 6, y = bid & 63;
  const int t = threadIdx.x;
  const int xx = t & 63, cg = t >> 6;      // cg: 8-channel group 0..3
  unsigned short h[8];
#pragma unroll
  for (int k = 0; k < 8; ++k) {
    const int c = cg * 8 + k;
    const float v = x[(((size_t)(b * 32 + c) * 64 + y) * 64) + xx];
    h[k] = f2bf(v / (1.0f + __expf(-v)));  // silu
    float bb[11];
#pragma unroll
    for (int i = 0; i < 11; ++i) {
      float t0 = -2.2f + 0.4f * i;
      bb[i] = (v >= t0 && v < t0 + 0.4f) ? 1.0f : 0.0f;
    }
#pragma unroll
    for (int j = 1; j <= 3; ++j) {
      float rj = 1.0f / (0.4f * j);
#pragma unroll
      for (int i = 0; i + j < 11; ++i) {
        float ti = -2.2f + 0.4f * i;
        bb[i] = (v - ti) * rj * bb[i] + ((ti + 0.4f * (j + 1)) - v) * rj * bb[i + 1];
      }
    }
    uint2 o;
    unsigned w0 = __builtin_amdgcn_cvt_pk_fp8_f32(bb[0], bb[1], 0, false);
    w0 = __builtin_amdgcn_cvt_pk_fp8_f32(bb[2], bb[3], w0, true);
    unsigned w1 = __builtin_amdgcn_cvt_pk_fp8_f32(bb[4], bb[5], 0, false);
    w1 = __builtin_amdgcn_cvt_pk_fp8_f32(bb[6], bb[7], w1, true);
    o.x = w0; o.y = w1;
    *(uint2*)(ws + FSPL8_OFF + ((((size_t)(b * 32 + c) * 64 + y) * 64) + xx) * 8) = o;
  }
  uint4 s;
  s.x = (unsigned)h[0] | ((unsigned)h[1] << 16);
  s.y = (unsigned)h[2] | ((unsigned)h[3] << 16);
  s.z = (unsigned)h[4] | ((unsigned)h[5] << 16);
  s.w = (unsigned)h[6] | ((unsigned)h[7] << 16);
  *(uint4*)(ws + FSILU_OFF + (size_t)(b * 4096 + y * 64 + xx) * 64 + cg * 16) = s;
}

// ---- kernel 2: pack weights (MX fp8 / leftover fp8 / silu bf16) ------------
__global__ __launch_bounds__(256) void k_wpack(const float* __restrict__ bw,
                                               const float* __restrict__ sw,
                                               const float* __restrict__ sc,
                                               unsigned char* __restrict__ ws) {
  int tid = blockIdx.x * 256 + threadIdx.x;
  if (tid >= 165888) return;
  if (tid < 147456) {                      // spline fp8: MX region + WF8 region
    int k, dst;
    if (tid < 131072) {                    // WMX [p][ss][ot][pc][lane][16]
      int bh = tid & 15, lane = (tid >> 4) & 63, pc = (tid >> 10) & 1;
      int ss = (tid >> 13) & 1, p = tid >> 14;
      k = p * 288 + ss * 128 + (lane >> 4) * 32 + pc * 16 + bh;
      dst = WMX_OFF + tid;
    } else {                               // WF8 [p][ot][lane][8]
      int t2 = tid - 131072;
      int e = t2 & 7, lane = (t2 >> 3) & 63, p = t2 >> 11;
      k = p * 288 + 256 + (lane >> 4) * 8 + e;
      dst = WF8_OFF + t2;
    }
    int ot = (tid < 131072) ? ((tid >> 11) & 3) : (((tid - 131072) >> 9) & 3);
    int lane = (tid < 131072) ? ((tid >> 4) & 63) : (((tid - 131072) >> 3) & 63);
    int o = (ot << 4) + (lane & 15);
    int chunk = k / 24, u = k - chunk * 24;
    int dj = u >> 3, g = u & 7;
    int c = chunk / 3, di = chunk - c * 3;
    int p_tap = di * 3 + dj;
    float val = sw[((size_t)(o * 32 + c) * 9 + p_tap) * 8 + g] *
                sc[(size_t)(o * 32 + c) * 9 + p_tap];
    ws[dst] = (unsigned char)(__builtin_amdgcn_cvt_pk_fp8_f32(val, 0.f, 0, false) & 0xff);
  } else {                                 // silu bf16: [sp9][ot4][lane64][e8]
    int t2 = tid - 147456;
    int e = t2 & 7, lane = (t2 >> 3) & 63, ot = (t2 >> 9) & 3, sp = t2 >> 11;
    int o = (ot << 4) + (lane & 15);
    int cc = ((lane >> 4) << 3) + e;
    float val = bw[(size_t)(o * 32 + cc) * 9 + sp];
    *(unsigned short*)(ws + WPACKS_OFF + (size_t)t2 * 2) = f2bf(val);
  }
}

// ---- async 16B global -> LDS (lds dest = wave-uniform base + lane*16) ------
__device__ __forceinline__ void ld16(unsigned char* ldsp, const unsigned char* gp) {
  __builtin_amdgcn_global_load_lds(
      (const __attribute__((address_space(1))) unsigned int*)gp,
      (__attribute__((address_space(3))) unsigned int*)ldsp, 16, 0, 0);
}

// ---- kernel 3: implicit GEMM; MX fp8 spline (dbuf) + bf16 silu (pre-staged)-
// Block: 8 waves = (r = w>>1 of 4 rows, oh = w&1 o-half), 256 blocks (1/CU).
// Period p: 2 MX supersteps (K=128) + 1 fp8 K=32 step. wl8 buf = 16 KB WMX[p]
// + 2 KB WF8[p]; fl8 = 4 c-planes x 6 rows x 512 B.
__global__ __launch_bounds__(512) void k_gemm(const unsigned char* __restrict__ ws,
                                              float* __restrict__ out) {
  __shared__ __align__(16) unsigned char wl8[2][18432];
  __shared__ __align__(16) unsigned char fl8[2][12544];
  __shared__ __align__(16) unsigned char wsil[36864];
  __shared__ __align__(16) unsigned char fsil[25088];

  const int blk = blockIdx.x;              // b*16 + ig
  const int b = blk >> 4, ig = blk & 15;
  const int i0 = ig * 4;
  const int tid = threadIdx.x;
  const int wave = tid >> 6, lane = tid & 63;
  const int q = lane >> 4, ln = lane & 15;
  const int r = wave >> 1, oh = wave & 1;
  const int i = i0 + r;

  auto stage_spl = [&](int p, int bi) {    // 30 chunks over 8 waves
#pragma unroll
    for (int it = 0; it < 4; ++it) {
      const int u = wave + it * 8;
      if (u < 16) {
        ld16(&wl8[bi][u * 1024], ws + WMX_OFF + (size_t)p * 16384 + (size_t)u * 1024 + lane * 16);
      } else if (u < 18) {
        ld16(&wl8[bi][u * 1024], ws + WF8_OFF + (size_t)p * 2048 + (size_t)(u - 16) * 1024 + lane * 16);
      } else if (u < 30) {
        const int v = u - 18;
        const int cp = v / 3, cr = v - cp * 3;     // rows {2cr, 2cr+1}
        ld16(&fl8[bi][v * 1024],
             ws + FSPL8_OFF + ((size_t)((b * 32 + p * 4 + cp) * 64 + i0 + cr * 2)) * 512 + lane * 16);
      }
    }
  };

  auto stage_silu = [&]() {                // 60 chunks over 8 waves
#pragma unroll
    for (int it = 0; it < 8; ++it) {
      const int u = wave + it * 8;
      if (u < 36) {
        ld16(&wsil[u * 1024], ws + WPACKS_OFF + (size_t)u * 1024 + lane * 16);
      } else if (u < 60) {
        const int v = u - 36;
        const int rr = v >> 2, p4 = v & 3;
        const int y = min(i0 + rr, 63);
        ld16(&fsil[v * 1024],
             ws + FSILU_OFF + (size_t)(b * 64 + y) * 4096 +
                 (p4 * 16 + (lane >> 2)) * 64 + ((lane & 3) ^ ((lane >> 2) & 3)) * 16);
      }
    }
  };

  // feature run offsets: off(sg, qq) for rid = 4*sg+qq
  auto offf = [&](int sg, int qq) {
    int rid = 4 * sg + qq;
    int ch = rid / 3, sub = rid - ch * 3;
    int cp = ch / 3, di = ch - cp * 3;
    return cp * 3072 + (r + di) * 512 + (sub + ln) * 8;
  };
  int offA[4], offB[4];
#pragma unroll
  for (int qq = 0; qq < 4; ++qq) { offA[qq] = offf(q, qq); offB[qq] = offf(4 + q, qq); }
  const int off8 = offf(8, q);

  v4f acc[2][4];
#pragma unroll
  for (int a = 0; a < 2; ++a)
#pragma unroll
    for (int c = 0; c < 4; ++c) acc[a][c] = (v4f){0.f, 0.f, 0.f, 0.f};

  stage_silu();
  stage_spl(0, 0);
  __syncthreads();

#pragma unroll 1
  for (int t = 0; t < 8; ++t) {
    if (t < 7) stage_spl(t + 1, (t + 1) & 1);
    const unsigned char* wb = wl8[t & 1];
    const unsigned char* fb = fl8[t & 1];
#pragma unroll
    for (int ss = 0; ss < 2; ++ss) {
      union { v8i v; v4i h[2]; } wf[2];
#pragma unroll
      for (int tt = 0; tt < 2; ++tt) {
        const unsigned char* wp = wb + ss * 8192 + (oh * 2 + tt) * 2048 + lane * 16;
        wf[tt].h[0] = *(const v4i*)(wp);
        wf[tt].h[1] = *(const v4i*)(wp + 1024);
      }
      const int* offs = ss ? offB : offA;
      union { v8i v; long l[4]; } ff[4];
#pragma unroll
      for (int pt = 0; pt < 4; ++pt)
#pragma unroll
        for (int qq = 0; qq < 4; ++qq)
          ff[pt].l[qq] = *(const long*)(fb + offs[qq] + pt * 128);
#pragma unroll
      for (int tt = 0; tt < 2; ++tt)
#pragma unroll
        for (int pt = 0; pt < 4; ++pt)
          acc[tt][pt] = __builtin_amdgcn_mfma_scale_f32_16x16x128_f8f6f4(
              wf[tt].v, ff[pt].v, acc[tt][pt], 0, 0, 0, SCALE1, 0, SCALE1);
    }
    {                                      // leftover fp8 K=32 step (sg=8)
      long w8[2], f8[4];
#pragma unroll
      for (int tt = 0; tt < 2; ++tt)
        w8[tt] = *(const long*)(wb + 16384 + (oh * 2 + tt) * 512 + lane * 8);
#pragma unroll
      for (int pt = 0; pt < 4; ++pt)
        f8[pt] = *(const long*)(fb + off8 + pt * 128);
#pragma unroll
      for (int tt = 0; tt < 2; ++tt)
#pragma unroll
        for (int pt = 0; pt < 4; ++pt)
          acc[tt][pt] = __builtin_amdgcn_mfma_f32_16x16x32_fp8_fp8(
              w8[tt], f8[pt], acc[tt][pt], 0, 0, 0);
    }
    __syncthreads();
  }

  // ---- silu phase: bf16, from pre-staged buffers ---------------------------
#pragma unroll
  for (int e = 0; e < 9; ++e) {
    const int di = e / 3, dj = e % 3;
    v8s wb2[2], fb2[4];
#pragma unroll
    for (int tt = 0; tt < 2; ++tt)
      wb2[tt] = *(const v8s*)(&wsil[0] + e * 4096 + (oh * 2 + tt) * 1024 + lane * 16);
    const int xb = dj + ln;
    const int sbase = (r + di) * 4096 + xb * 64 + ((q ^ (xb & 3)) * 16);
#pragma unroll
    for (int pt = 0; pt < 4; ++pt)
      fb2[pt] = *(const v8s*)(&fsil[0] + sbase + pt * 1024);
#pragma unroll
    for (int tt = 0; tt < 2; ++tt)
#pragma unroll
      for (int pt = 0; pt < 4; ++pt)
        acc[tt][pt] = __builtin_amdgcn_mfma_f32_16x16x32_bf16(
            wb2[tt], fb2[pt], acc[tt][pt], 0, 0, 0);
  }

  // ---- epilogue: C/D layout col(n=j)=lane&15, row(m=o)=q*4+reg -------------
  if (i < 62) {
#pragma unroll
    for (int tt = 0; tt < 2; ++tt)
#pragma unroll
      for (int pt = 0; pt < 4; ++pt) {
        const int j = pt * 16 + ln;
        if (j < 62) {
#pragma unroll
          for (int rr = 0; rr < 4; ++rr) {
            const int o = (oh * 2 + tt) * 16 + q * 4 + rr;
            out[(((size_t)b * 64 + o) * 62 + i) * 62 + j] = acc[tt][pt][rr];
          }
        }
      }
  }
}

extern "C" void kernel_launch(void* const* d_in, const int* in_sizes, int n_in,
                              void* d_out, int out_size, void* d_ws, size_t ws_size,
                              hipStream_t stream) {
  const float* x  = (const float*)d_in[0];
  const float* bw = (const float*)d_in[1];
  const float* sw = (const float*)d_in[2];
  const float* sc = (const float*)d_in[3];
  unsigned char* ws = (unsigned char*)d_ws;
  float* out = (float*)d_out;

  hipLaunchKernelGGL(k_feat,  dim3(1024), dim3(256), 0, stream, x, ws);
  hipLaunchKernelGGL(k_wpack, dim3(648),  dim3(256), 0, stream, bw, sw, sc, ws);
  hipLaunchKernelGGL(k_gemm,  dim3(256),  dim3(512), 0, stream, ws, out);
}